// Round 5
// baseline (980.609 us; speedup 1.0000x reference)
//
#include <hip/hip_runtime.h>

#define F_IN 512
#define HID  16
#define NCLS 40
#define BSH2 8            // 256 nodes per bucket
#define BNODES 256
#define NBMAX 512         // LDS array bound (>= nbuckets = 391)
#define ASTR 17           // padded LDS acc stride (bank spread)
#define EPB 8192          // edges per k_bucket block

__global__ void k_zero_i(int* __restrict__ p, int n) {
    int i = blockIdx.x * blockDim.x + threadIdx.x;
    if (i < n) p[i] = 0;
}

// cnt[col[e]] += 1  (int atomics, 1 per edge, int4 loads)
__global__ void k_hist(const int* __restrict__ col, int* __restrict__ cnt, int ne) {
    int i = blockIdx.x * blockDim.x + threadIdx.x;
    int e0 = i * 4;
    if (e0 + 3 < ne) {
        int4 c = *reinterpret_cast<const int4*>(col + e0);
        atomicAdd(&cnt[c.x], 1);
        atomicAdd(&cnt[c.y], 1);
        atomicAdd(&cnt[c.z], 1);
        atomicAdd(&cnt[c.w], 1);
    } else {
        for (int e = e0; e < ne; ++e) atomicAdd(&cnt[col[e]], 1);
    }
}

// per-bucket edge counts: block b sums cnt[b*256 .. b*256+255]
__global__ void k_bsum(const int* __restrict__ cnt, int* __restrict__ bcnt, int n) {
    int b = blockIdx.x, t = threadIdx.x;
    int base = (b << BSH2) + t * 4;
    int end = min(n, (b + 1) << BSH2);
    int s = 0;
    if (base + 3 < end) {
        int4 c = *reinterpret_cast<const int4*>(cnt + base);
        s = c.x + c.y + c.z + c.w;
    } else {
        for (int i = base; i < end && i < base + 4; ++i) s += cnt[i];
    }
    for (int off = 32; off > 0; off >>= 1) s += __shfl_down(s, off, 64);
    if (t == 0) bcnt[b] = s;
}

// single tiny block: exclusive scan of bucket counts -> bstart (+ total), bcur copy
__global__ void k_bscan(const int* __restrict__ bcnt, int* __restrict__ bstart,
                        int* __restrict__ bcur, int nb) {
    __shared__ int sh[512];
    int t = threadIdx.x;
    int v = (t < nb) ? bcnt[t] : 0;
    sh[t] = v;
    __syncthreads();
    for (int off = 1; off < 512; off <<= 1) {
        int u = (t >= off) ? sh[t - off] : 0;
        __syncthreads();
        sh[t] += u;
        __syncthreads();
    }
    if (t < nb) {
        int ex = sh[t] - v;
        bstart[t] = ex;
        bcur[t] = ex;
    }
    if (t == nb - 1) bstart[nb] = sh[t];
}

// two-pass bucket partition: count -> allocate -> write (row,col) into bucket regions
__global__ void k_bucket(const int* __restrict__ row, const int* __restrict__ col,
                         int* __restrict__ bcur, int2* __restrict__ pairs, int ne) {
    __shared__ int lhist[NBMAX];
    __shared__ int gbase[NBMAX];
    __shared__ int lcur[NBMAX];
    int t = threadIdx.x;
    for (int i = t; i < NBMAX; i += 256) { lhist[i] = 0; lcur[i] = 0; }
    __syncthreads();
    int base = blockIdx.x * EPB;
    int end = min(ne, base + EPB);
    for (int e = base + t; e < end; e += 256)
        atomicAdd(&lhist[col[e] >> BSH2], 1);
    __syncthreads();
    for (int i = t; i < NBMAX; i += 256)
        if (lhist[i] > 0) gbase[i] = atomicAdd(&bcur[i], lhist[i]);
    __syncthreads();
    for (int e = base + t; e < end; e += 256) {
        int r = row[e], c = col[e];
        int gb = c >> BSH2;
        int rk = atomicAdd(&lcur[gb], 1);
        pairs[gbase[gb] + rk] = make_int2(r, c);
    }
}

// yp = dinv[node] * (x @ W1)   (prescaled by source dinv; dinv from cnt on the fly)
__global__ void k_gemm1(const float* __restrict__ x, const float* __restrict__ W1,
                        const int* __restrict__ cnt, float* __restrict__ yp, int n) {
    int node = blockIdx.x * blockDim.x + threadIdx.x;
    if (node >= n) return;
    const float* xr = x + (size_t)node * F_IN;
    float acc[HID];
#pragma unroll
    for (int j = 0; j < HID; ++j) acc[j] = 0.f;
    for (int k = 0; k < F_IN; k += 4) {
        float4 xv = *reinterpret_cast<const float4*>(xr + k);
        const float* w = W1 + (size_t)k * HID;
#pragma unroll
        for (int j = 0; j < HID; ++j) acc[j] = fmaf(xv.x, w[j], acc[j]);
#pragma unroll
        for (int j = 0; j < HID; ++j) acc[j] = fmaf(xv.y, w[HID + j], acc[j]);
#pragma unroll
        for (int j = 0; j < HID; ++j) acc[j] = fmaf(xv.z, w[2 * HID + j], acc[j]);
#pragma unroll
        for (int j = 0; j < HID; ++j) acc[j] = fmaf(xv.w, w[3 * HID + j], acc[j]);
    }
    float di = rsqrtf((float)(cnt[node] + 1));
    float4* o = reinterpret_cast<float4*>(yp + (size_t)node * HID);
#pragma unroll
    for (int q = 0; q < 4; ++q)
        o[q] = make_float4(acc[4 * q] * di, acc[4 * q + 1] * di,
                           acc[4 * q + 2] * di, acc[4 * q + 3] * di);
}

// per-bucket LDS scatter-aggregate: block b owns nodes [b*256, b*256+256)
// acc[c] = sum over in-edges of src[r]; out = dinv*(acc + src[c]) [+bias/relu/prescale]
template <bool RELU>
__global__ __launch_bounds__(512) void k_agg_lds(
    const int* __restrict__ bstart, const int2* __restrict__ pairs,
    const float* __restrict__ src, const int* __restrict__ cnt,
    const float* __restrict__ b1, float* __restrict__ dst, int n) {
    __shared__ float acc[BNODES * ASTR];
    int b = blockIdx.x, t = threadIdx.x;
    int c0 = b << BSH2;
    int nloc = min(BNODES, n - c0);
    for (int i = t; i < BNODES * ASTR; i += 512) acc[i] = 0.f;
    __syncthreads();
    int s = bstart[b], e = bstart[b + 1];
    for (int k = s + t; k < e; k += 512) {
        int2 pc = pairs[k];
        const float4* yr = reinterpret_cast<const float4*>(src + (size_t)pc.x * HID);
        float4 v0 = yr[0], v1 = yr[1], v2 = yr[2], v3 = yr[3];
        float* a = &acc[(pc.y - c0) * ASTR];
        atomicAdd(a + 0,  v0.x); atomicAdd(a + 1,  v0.y);
        atomicAdd(a + 2,  v0.z); atomicAdd(a + 3,  v0.w);
        atomicAdd(a + 4,  v1.x); atomicAdd(a + 5,  v1.y);
        atomicAdd(a + 6,  v1.z); atomicAdd(a + 7,  v1.w);
        atomicAdd(a + 8,  v2.x); atomicAdd(a + 9,  v2.y);
        atomicAdd(a + 10, v2.z); atomicAdd(a + 11, v2.w);
        atomicAdd(a + 12, v3.x); atomicAdd(a + 13, v3.y);
        atomicAdd(a + 14, v3.z); atomicAdd(a + 15, v3.w);
    }
    __syncthreads();
    int i = t >> 1;
    if (i < nloc) {
        int c = c0 + i;
        int j0 = (t & 1) * 8;
        float d = rsqrtf((float)(cnt[c] + 1));
        const float* sl = src + (size_t)c * HID + j0;   // self-loop (prescaled)
        float o[8];
#pragma unroll
        for (int j = 0; j < 8; ++j) {
            float v = acc[i * ASTR + j0 + j] + sl[j];
            if (RELU) v = fmaxf(fmaf(d, v, b1[j0 + j]), 0.f) * d;
            else      v = d * v;
            o[j] = v;
        }
        float4* op = reinterpret_cast<float4*>(dst + (size_t)c * HID + j0);
        op[0] = make_float4(o[0], o[1], o[2], o[3]);
        op[1] = make_float4(o[4], o[5], o[6], o[7]);
    }
}

// out = log_softmax(agg2 @ W2 + b2)
__global__ void k_final(const float* __restrict__ agg2, const float* __restrict__ W2,
                        const float* __restrict__ b2, float* __restrict__ out, int n) {
    int node = blockIdx.x * blockDim.x + threadIdx.x;
    if (node >= n) return;
    const float4* ar = reinterpret_cast<const float4*>(agg2 + (size_t)node * HID);
    float a[HID];
#pragma unroll
    for (int q = 0; q < 4; ++q) {
        float4 t = ar[q];
        a[4 * q] = t.x; a[4 * q + 1] = t.y; a[4 * q + 2] = t.z; a[4 * q + 3] = t.w;
    }
    float z[NCLS];
#pragma unroll
    for (int j = 0; j < NCLS; ++j) z[j] = b2[j];
#pragma unroll
    for (int i = 0; i < HID; ++i) {
        const float* w = W2 + (size_t)i * NCLS;
        float ai = a[i];
#pragma unroll
        for (int j = 0; j < NCLS; ++j) z[j] = fmaf(ai, w[j], z[j]);
    }
    float m = z[0];
#pragma unroll
    for (int j = 1; j < NCLS; ++j) m = fmaxf(m, z[j]);
    float s = 0.f;
#pragma unroll
    for (int j = 0; j < NCLS; ++j) s += __expf(z[j] - m);
    float ls = m + __logf(s);
    float* o = out + (size_t)node * NCLS;
#pragma unroll
    for (int q = 0; q < NCLS / 4; ++q)
        *reinterpret_cast<float4*>(o + 4 * q) =
            make_float4(z[4 * q] - ls, z[4 * q + 1] - ls, z[4 * q + 2] - ls, z[4 * q + 3] - ls);
}

extern "C" void kernel_launch(void* const* d_in, const int* in_sizes, int n_in,
                              void* d_out, int out_size, void* d_ws, size_t ws_size,
                              hipStream_t stream) {
    const float* x  = (const float*)d_in[0];
    const int*   ei = (const int*)d_in[1];
    const float* W1 = (const float*)d_in[2];
    const float* b1 = (const float*)d_in[3];
    const float* W2 = (const float*)d_in[4];
    const float* b2 = (const float*)d_in[5];
    float* out = (float*)d_out;

    const int N = in_sizes[0] / F_IN;   // 100000
    const int E = in_sizes[1] / 2;      // 3200000
    const int* row = ei;        // source nodes
    const int* col = ei + E;    // target nodes
    const int NBUCK = (N + BNODES - 1) >> BSH2;   // 391

    // workspace layout (agg2 aliases yp — yp dead after layer-1 agg)
    char* w = (char*)d_ws;
    int*   cnt    = (int*)w;   w += (size_t)N * 4;
    int*   bcnt   = (int*)w;   w += (size_t)NBMAX * 4;
    int*   bstart = (int*)w;   w += (size_t)(NBMAX + 1) * 4;
    int*   bcur   = (int*)w;   w += (size_t)NBMAX * 4;
    int2*  pairs  = (int2*)w;  w += (size_t)E * 8;
    float* yp     = (float*)w; w += (size_t)N * HID * 4;
    float* hp     = (float*)w; w += (size_t)N * HID * 4;
    float* agg2   = yp;        // alias

    const int B = 256;
    k_zero_i<<<(N + B - 1) / B, B, 0, stream>>>(cnt, N);
    k_hist  <<<((E + 3) / 4 + B - 1) / B, B, 0, stream>>>(col, cnt, E);
    k_bsum  <<<NBUCK, 64, 0, stream>>>(cnt, bcnt, N);
    k_bscan <<<1, 512, 0, stream>>>(bcnt, bstart, bcur, NBUCK);
    k_bucket<<<(E + EPB - 1) / EPB, B, 0, stream>>>(row, col, bcur, pairs, E);
    k_gemm1 <<<(N + B - 1) / B, B, 0, stream>>>(x, W1, cnt, yp, N);
    k_agg_lds<true> <<<NBUCK, 512, 0, stream>>>(bstart, pairs, yp, cnt, b1, hp, N);
    k_agg_lds<false><<<NBUCK, 512, 0, stream>>>(bstart, pairs, hp, cnt, nullptr, agg2, N);
    k_final <<<(N + B - 1) / B, B, 0, stream>>>(agg2, W2, b2, out, N);
}

// Round 6
// 451.009 us; speedup vs baseline: 2.1743x; 2.1743x over previous
//
#include <hip/hip_runtime.h>

#define F_IN 512
#define HID  16
#define NCLS 40
#define BSH2 8            // 256 nodes per bucket
#define BNODES 256
#define NBMAX 512         // >= nbuckets = 391
#define EPB 8192          // edges per k_bucket block
#define CAP 12288         // LDS row buffer capacity (mean 8192, sigma~90)

__global__ void k_zero_i(int* __restrict__ p, int n) {
    int i = blockIdx.x * blockDim.x + threadIdx.x;
    if (i < n) p[i] = 0;
}

// cnt[col[e]] += 1  (int atomics, 1 per edge, int4 loads)
__global__ void k_hist(const int* __restrict__ col, int* __restrict__ cnt, int ne) {
    int i = blockIdx.x * blockDim.x + threadIdx.x;
    int e0 = i * 4;
    if (e0 + 3 < ne) {
        int4 c = *reinterpret_cast<const int4*>(col + e0);
        atomicAdd(&cnt[c.x], 1);
        atomicAdd(&cnt[c.y], 1);
        atomicAdd(&cnt[c.z], 1);
        atomicAdd(&cnt[c.w], 1);
    } else {
        for (int e = e0; e < ne; ++e) atomicAdd(&cnt[col[e]], 1);
    }
}

// per-bucket edge counts: block b sums cnt[b*256 .. b*256+255]
__global__ void k_bsum(const int* __restrict__ cnt, int* __restrict__ bcnt, int n) {
    int b = blockIdx.x, t = threadIdx.x;
    int base = (b << BSH2) + t * 4;
    int end = min(n, (b + 1) << BSH2);
    int s = 0;
    if (base + 3 < end) {
        int4 c = *reinterpret_cast<const int4*>(cnt + base);
        s = c.x + c.y + c.z + c.w;
    } else {
        for (int i = base; i < end && i < base + 4; ++i) s += cnt[i];
    }
    for (int off = 32; off > 0; off >>= 1) s += __shfl_down(s, off, 64);
    if (t == 0) bcnt[b] = s;
}

// single tiny block: exclusive scan of bucket counts -> bstart (+ total), bcur copy
__global__ void k_bscan(const int* __restrict__ bcnt, int* __restrict__ bstart,
                        int* __restrict__ bcur, int nb) {
    __shared__ int sh[512];
    int t = threadIdx.x;
    int v = (t < nb) ? bcnt[t] : 0;
    sh[t] = v;
    __syncthreads();
    for (int off = 1; off < 512; off <<= 1) {
        int u = (t >= off) ? sh[t - off] : 0;
        __syncthreads();
        sh[t] += u;
        __syncthreads();
    }
    if (t < nb) {
        int ex = sh[t] - v;
        bstart[t] = ex;
        bcur[t] = ex;
    }
    if (t == nb - 1) bstart[nb] = sh[t];
}

// two-pass bucket partition: count -> allocate -> write (row,col) into bucket regions
__global__ void k_bucket(const int* __restrict__ row, const int* __restrict__ col,
                         int* __restrict__ bcur, int2* __restrict__ pairs, int ne) {
    __shared__ int lhist[NBMAX];
    __shared__ int gbase[NBMAX];
    __shared__ int lcur[NBMAX];
    int t = threadIdx.x;
    for (int i = t; i < NBMAX; i += 256) { lhist[i] = 0; lcur[i] = 0; }
    __syncthreads();
    int base = blockIdx.x * EPB;
    int end = min(ne, base + EPB);
    for (int e = base + t; e < end; e += 256)
        atomicAdd(&lhist[col[e] >> BSH2], 1);
    __syncthreads();
    for (int i = t; i < NBMAX; i += 256)
        if (lhist[i] > 0) gbase[i] = atomicAdd(&bcur[i], lhist[i]);
    __syncthreads();
    for (int e = base + t; e < end; e += 256) {
        int r = row[e], c = col[e];
        int gb = c >> BSH2;
        int rk = atomicAdd(&lcur[gb], 1);
        pairs[gbase[gb] + rk] = make_int2(r, c);
    }
}

// per-bucket CSR finalize: local scan of cnt -> ptr; LDS-scatter pairs -> coalesced rows_sorted
__global__ __launch_bounds__(512) void k_csr(
    const int* __restrict__ cnt, const int* __restrict__ bstart,
    const int2* __restrict__ pairs, int* __restrict__ ptr,
    int* __restrict__ rows_sorted, int n, int nb) {
    __shared__ int sh[BNODES];
    __shared__ int lcur[BNODES];
    __shared__ int lrows[CAP];
    int b = blockIdx.x, t = threadIdx.x;
    int c0 = b << BSH2;
    int nloc = min(BNODES, n - c0);
    int s = bstart[b], e = bstart[b + 1];
    int own = 0;
    if (t < BNODES) {
        own = (t < nloc) ? cnt[c0 + t] : 0;
        sh[t] = own;
    }
    __syncthreads();
    // Hillis-Steele inclusive scan over 256 entries (all 512 threads hit barriers)
    for (int off = 1; off < BNODES; off <<= 1) {
        int v = (t >= off && t < BNODES) ? sh[t - off] : 0;
        __syncthreads();
        if (t < BNODES) sh[t] += v;
        __syncthreads();
    }
    if (t < nloc) {
        int ex = sh[t] - own;
        ptr[c0 + t] = s + ex;
        lcur[t] = ex;
    }
    if (b == nb - 1 && t == 0) ptr[n] = e;
    __syncthreads();
    int m = e - s;
    if (m <= CAP) {
        for (int k = t; k < m; k += 512) {
            int2 pc = pairs[s + k];
            int pos = atomicAdd(&lcur[pc.y - c0], 1);
            lrows[pos] = pc.x;
        }
        __syncthreads();
        for (int k = t; k < m; k += 512) rows_sorted[s + k] = lrows[k];
    } else {  // freak-bucket fallback: direct global scatter (correct, slower)
        for (int k = t; k < m; k += 512) {
            int2 pc = pairs[s + k];
            int pos = atomicAdd(&lcur[pc.y - c0], 1);
            rows_sorted[s + pos] = pc.x;
        }
    }
}

// yp = dinv[node] * (x @ W1)   (prescaled by source dinv; dinv from cnt on the fly)
__global__ void k_gemm1(const float* __restrict__ x, const float* __restrict__ W1,
                        const int* __restrict__ cnt, float* __restrict__ yp, int n) {
    int node = blockIdx.x * blockDim.x + threadIdx.x;
    if (node >= n) return;
    const float* xr = x + (size_t)node * F_IN;
    float acc[HID];
#pragma unroll
    for (int j = 0; j < HID; ++j) acc[j] = 0.f;
    for (int k = 0; k < F_IN; k += 4) {
        float4 xv = *reinterpret_cast<const float4*>(xr + k);
        const float* w = W1 + (size_t)k * HID;
#pragma unroll
        for (int j = 0; j < HID; ++j) acc[j] = fmaf(xv.x, w[j], acc[j]);
#pragma unroll
        for (int j = 0; j < HID; ++j) acc[j] = fmaf(xv.y, w[HID + j], acc[j]);
#pragma unroll
        for (int j = 0; j < HID; ++j) acc[j] = fmaf(xv.z, w[2 * HID + j], acc[j]);
#pragma unroll
        for (int j = 0; j < HID; ++j) acc[j] = fmaf(xv.w, w[3 * HID + j], acc[j]);
    }
    float di = rsqrtf((float)(cnt[node] + 1));
    float4* o = reinterpret_cast<float4*>(yp + (size_t)node * HID);
#pragma unroll
    for (int q = 0; q < 4; ++q)
        o[q] = make_float4(acc[4 * q] * di, acc[4 * q + 1] * di,
                           acc[4 * q + 2] * di, acc[4 * q + 3] * di);
}

// Gather-reduce over CSR segment. 4 lanes per node, each lane owns a float4.
template <bool RELU>
__global__ void k_agg(const int* __restrict__ ptr, const int* __restrict__ rows_sorted,
                      const float* __restrict__ src, const int* __restrict__ cnt,
                      const float* __restrict__ b1, float* __restrict__ dst, int n) {
    int t = blockIdx.x * blockDim.x + threadIdx.x;
    int g = t >> 2;            // node
    if (g >= n) return;
    int q = (t & 3) << 2;      // float4 slot
    float4 acc = *reinterpret_cast<const float4*>(src + (size_t)g * HID + q);
    int s = ptr[g], e2 = ptr[g + 1];
    int k = s;
    for (; k + 1 < e2; k += 2) {
        int r0 = rows_sorted[k], r1 = rows_sorted[k + 1];
        float4 v0 = *reinterpret_cast<const float4*>(src + (size_t)r0 * HID + q);
        float4 v1 = *reinterpret_cast<const float4*>(src + (size_t)r1 * HID + q);
        acc.x += v0.x + v1.x; acc.y += v0.y + v1.y;
        acc.z += v0.z + v1.z; acc.w += v0.w + v1.w;
    }
    if (k < e2) {
        int r0 = rows_sorted[k];
        float4 v0 = *reinterpret_cast<const float4*>(src + (size_t)r0 * HID + q);
        acc.x += v0.x; acc.y += v0.y; acc.z += v0.z; acc.w += v0.w;
    }
    float d = rsqrtf((float)(cnt[g] + 1));
    float4 o;
    if (RELU) {
        float4 bb = *reinterpret_cast<const float4*>(b1 + q);
        o.x = d * fmaxf(fmaf(d, acc.x, bb.x), 0.f);
        o.y = d * fmaxf(fmaf(d, acc.y, bb.y), 0.f);
        o.z = d * fmaxf(fmaf(d, acc.z, bb.z), 0.f);
        o.w = d * fmaxf(fmaf(d, acc.w, bb.w), 0.f);
    } else {
        o.x = d * acc.x; o.y = d * acc.y; o.z = d * acc.z; o.w = d * acc.w;
    }
    *reinterpret_cast<float4*>(dst + (size_t)g * HID + q) = o;
}

// out = log_softmax(agg2 @ W2 + b2)
__global__ void k_final(const float* __restrict__ agg2, const float* __restrict__ W2,
                        const float* __restrict__ b2, float* __restrict__ out, int n) {
    int node = blockIdx.x * blockDim.x + threadIdx.x;
    if (node >= n) return;
    const float4* ar = reinterpret_cast<const float4*>(agg2 + (size_t)node * HID);
    float a[HID];
#pragma unroll
    for (int q = 0; q < 4; ++q) {
        float4 t = ar[q];
        a[4 * q] = t.x; a[4 * q + 1] = t.y; a[4 * q + 2] = t.z; a[4 * q + 3] = t.w;
    }
    float z[NCLS];
#pragma unroll
    for (int j = 0; j < NCLS; ++j) z[j] = b2[j];
#pragma unroll
    for (int i = 0; i < HID; ++i) {
        const float* w = W2 + (size_t)i * NCLS;
        float ai = a[i];
#pragma unroll
        for (int j = 0; j < NCLS; ++j) z[j] = fmaf(ai, w[j], z[j]);
    }
    float m = z[0];
#pragma unroll
    for (int j = 1; j < NCLS; ++j) m = fmaxf(m, z[j]);
    float s = 0.f;
#pragma unroll
    for (int j = 0; j < NCLS; ++j) s += __expf(z[j] - m);
    float ls = m + __logf(s);
    float* o = out + (size_t)node * NCLS;
#pragma unroll
    for (int q = 0; q < NCLS / 4; ++q)
        *reinterpret_cast<float4*>(o + 4 * q) =
            make_float4(z[4 * q] - ls, z[4 * q + 1] - ls, z[4 * q + 2] - ls, z[4 * q + 3] - ls);
}

extern "C" void kernel_launch(void* const* d_in, const int* in_sizes, int n_in,
                              void* d_out, int out_size, void* d_ws, size_t ws_size,
                              hipStream_t stream) {
    const float* x  = (const float*)d_in[0];
    const int*   ei = (const int*)d_in[1];
    const float* W1 = (const float*)d_in[2];
    const float* b1 = (const float*)d_in[3];
    const float* W2 = (const float*)d_in[4];
    const float* b2 = (const float*)d_in[5];
    float* out = (float*)d_out;

    const int N = in_sizes[0] / F_IN;   // 100000
    const int E = in_sizes[1] / 2;      // 3200000
    const int* row = ei;        // source nodes
    const int* col = ei + E;    // target nodes
    const int NBUCK = (N + BNODES - 1) >> BSH2;   // 391

    // workspace: yp/hp/agg2 alias pairs (dead after k_csr)
    char* w = (char*)d_ws;
    int*   cnt    = (int*)w;   w += (size_t)N * 4;
    int*   bcnt   = (int*)w;   w += (size_t)NBMAX * 4;
    int*   bstart = (int*)w;   w += (size_t)(NBMAX + 1) * 4;
    int*   bcur   = (int*)w;   w += (size_t)NBMAX * 4;
    int*   ptr    = (int*)w;   w += (size_t)(N + 1) * 4;
    int*   rows_sorted = (int*)w; w += (size_t)E * 4;
    char*  uni    = w;         // union region: pairs (2E ints) vs yp+hp (32N floats)
    int2*  pairs  = (int2*)uni;
    float* yp     = (float*)uni;
    float* hp     = yp + (size_t)N * HID;
    float* agg2   = yp;        // alias (yp dead after layer-1 agg)

    const int B = 256;
    k_zero_i<<<(N + B - 1) / B, B, 0, stream>>>(cnt, N);
    k_hist  <<<((E + 3) / 4 + B - 1) / B, B, 0, stream>>>(col, cnt, E);
    k_bsum  <<<NBUCK, 64, 0, stream>>>(cnt, bcnt, N);
    k_bscan <<<1, 512, 0, stream>>>(bcnt, bstart, bcur, NBUCK);
    k_bucket<<<(E + EPB - 1) / EPB, B, 0, stream>>>(row, col, bcur, pairs, E);
    k_csr   <<<NBUCK, 512, 0, stream>>>(cnt, bstart, pairs, ptr, rows_sorted, N, NBUCK);
    k_gemm1 <<<(N + B - 1) / B, B, 0, stream>>>(x, W1, cnt, yp, N);
    k_agg<true> <<<((N * 4) + B - 1) / B, B, 0, stream>>>(ptr, rows_sorted, yp, cnt, b1, hp, N);
    k_agg<false><<<((N * 4) + B - 1) / B, B, 0, stream>>>(ptr, rows_sorted, hp, cnt, nullptr, agg2, N);
    k_final <<<(N + B - 1) / B, B, 0, stream>>>(agg2, W2, b2, out, N);
}

// Round 7
// 442.209 us; speedup vs baseline: 2.2175x; 1.0199x over previous
//
#include <hip/hip_runtime.h>

#define F_IN 512
#define HID  16
#define NCLS 40
#define BSH2 8            // 256 nodes per bucket
#define BNODES 256
#define NBMAX 512         // >= nbuckets = 391
#define EPB 8192          // edges per k_bucket/k_bhist block
#define CAP 12288         // LDS row buffer capacity (mean 8184, sigma~90)

__global__ void k_zero_i(int* __restrict__ p, int n) {
    int i = blockIdx.x * blockDim.x + threadIdx.x;
    if (i < n) p[i] = 0;
}

// per-bucket histogram via LDS: ~391 global atomics per block instead of 8192
__global__ void k_bhist(const int* __restrict__ col, int* __restrict__ bcnt, int ne) {
    __shared__ int lh[NBMAX];
    int t = threadIdx.x;
    for (int i = t; i < NBMAX; i += 256) lh[i] = 0;
    __syncthreads();
    int base = blockIdx.x * EPB;
    int end = min(ne, base + EPB);
    int e = base + t * 4;
    for (; e + 3 < end; e += 1024) {
        int4 c = *reinterpret_cast<const int4*>(col + e);
        atomicAdd(&lh[c.x >> BSH2], 1);
        atomicAdd(&lh[c.y >> BSH2], 1);
        atomicAdd(&lh[c.z >> BSH2], 1);
        atomicAdd(&lh[c.w >> BSH2], 1);
    }
    for (; e < end; ++e) atomicAdd(&lh[col[e] >> BSH2], 1);
    __syncthreads();
    for (int i = t; i < NBMAX; i += 256)
        if (lh[i] > 0) atomicAdd(&bcnt[i], lh[i]);
}

// single tiny block: exclusive scan of bucket counts -> bstart (+ total), bcur copy
__global__ void k_bscan(const int* __restrict__ bcnt, int* __restrict__ bstart,
                        int* __restrict__ bcur, int nb) {
    __shared__ int sh[512];
    int t = threadIdx.x;
    int v = (t < nb) ? bcnt[t] : 0;
    sh[t] = v;
    __syncthreads();
    for (int off = 1; off < 512; off <<= 1) {
        int u = (t >= off) ? sh[t - off] : 0;
        __syncthreads();
        sh[t] += u;
        __syncthreads();
    }
    if (t < nb) {
        int ex = sh[t] - v;
        bstart[t] = ex;
        bcur[t] = ex;
    }
    if (t == nb - 1) bstart[nb] = sh[t];
}

// two-pass bucket partition: count -> allocate -> write rows_raw (int) + lcol (uchar)
__global__ void k_bucket(const int* __restrict__ row, const int* __restrict__ col,
                         int* __restrict__ bcur, int* __restrict__ rows_raw,
                         unsigned char* __restrict__ lcol, int ne) {
    __shared__ int lhist[NBMAX];
    __shared__ int gbase[NBMAX];
    __shared__ int lcur[NBMAX];
    int t = threadIdx.x;
    for (int i = t; i < NBMAX; i += 256) { lhist[i] = 0; lcur[i] = 0; }
    __syncthreads();
    int base = blockIdx.x * EPB;
    int end = min(ne, base + EPB);
    for (int e = base + t; e < end; e += 256)
        atomicAdd(&lhist[col[e] >> BSH2], 1);
    __syncthreads();
    for (int i = t; i < NBMAX; i += 256)
        if (lhist[i] > 0) gbase[i] = atomicAdd(&bcur[i], lhist[i]);
    __syncthreads();
    for (int e = base + t; e < end; e += 256) {
        int r = row[e], c = col[e];
        int gb = c >> BSH2;
        int rk = atomicAdd(&lcur[gb], 1);
        int p = gbase[gb] + rk;
        rows_raw[p] = r;
        lcol[p] = (unsigned char)(c & (BNODES - 1));
    }
}

// per-bucket CSR finalize: LDS count -> cnt + ptr; LDS-scatter -> coalesced rows_sorted
__global__ __launch_bounds__(512) void k_csr(
    int* __restrict__ cnt, const int* __restrict__ bstart,
    const int* __restrict__ rows_raw, const unsigned char* __restrict__ lcol,
    int* __restrict__ ptr, int* __restrict__ rows_sorted, int n, int nb) {
    __shared__ int sh[BNODES];
    __shared__ int lcur[BNODES];
    __shared__ int lrows[CAP];
    int b = blockIdx.x, t = threadIdx.x;
    int c0 = b << BSH2;
    int nloc = min(BNODES, n - c0);
    int s = bstart[b], e = bstart[b + 1];
    int m = e - s;
    if (t < BNODES) sh[t] = 0;
    __syncthreads();
    // counting pass over this bucket's edges (LDS atomics)
    for (int k = t; k < m; k += 512) atomicAdd(&sh[lcol[s + k]], 1);
    __syncthreads();
    int own = (t < BNODES) ? sh[t] : 0;
    if (t < nloc) cnt[c0 + t] = own;
    // Hillis-Steele inclusive scan over 256 entries (all 512 threads hit barriers)
    for (int off = 1; off < BNODES; off <<= 1) {
        int v = (t >= off && t < BNODES) ? sh[t - off] : 0;
        __syncthreads();
        if (t < BNODES) sh[t] += v;
        __syncthreads();
    }
    if (t < nloc) {
        int ex = sh[t] - own;
        ptr[c0 + t] = s + ex;
        lcur[t] = ex;
    }
    if (b == nb - 1 && t == 0) ptr[n] = e;
    __syncthreads();
    if (m <= CAP) {
        for (int k = t; k < m; k += 512) {
            int pos = atomicAdd(&lcur[lcol[s + k]], 1);
            lrows[pos] = rows_raw[s + k];
        }
        __syncthreads();
        for (int k = t; k < m; k += 512) rows_sorted[s + k] = lrows[k];
    } else {  // freak-bucket fallback: direct global scatter (correct, slower)
        for (int k = t; k < m; k += 512) {
            int pos = atomicAdd(&lcur[lcol[s + k]], 1);
            rows_sorted[s + pos] = rows_raw[s + k];
        }
    }
}

// yp = dinv[node] * (x @ W1)   (prescaled by source dinv; dinv from cnt on the fly)
__global__ void k_gemm1(const float* __restrict__ x, const float* __restrict__ W1,
                        const int* __restrict__ cnt, float* __restrict__ yp, int n) {
    int node = blockIdx.x * blockDim.x + threadIdx.x;
    if (node >= n) return;
    const float* xr = x + (size_t)node * F_IN;
    float acc[HID];
#pragma unroll
    for (int j = 0; j < HID; ++j) acc[j] = 0.f;
    for (int k = 0; k < F_IN; k += 4) {
        float4 xv = *reinterpret_cast<const float4*>(xr + k);
        const float* w = W1 + (size_t)k * HID;
#pragma unroll
        for (int j = 0; j < HID; ++j) acc[j] = fmaf(xv.x, w[j], acc[j]);
#pragma unroll
        for (int j = 0; j < HID; ++j) acc[j] = fmaf(xv.y, w[HID + j], acc[j]);
#pragma unroll
        for (int j = 0; j < HID; ++j) acc[j] = fmaf(xv.z, w[2 * HID + j], acc[j]);
#pragma unroll
        for (int j = 0; j < HID; ++j) acc[j] = fmaf(xv.w, w[3 * HID + j], acc[j]);
    }
    float di = rsqrtf((float)(cnt[node] + 1));
    float4* o = reinterpret_cast<float4*>(yp + (size_t)node * HID);
#pragma unroll
    for (int q = 0; q < 4; ++q)
        o[q] = make_float4(acc[4 * q] * di, acc[4 * q + 1] * di,
                           acc[4 * q + 2] * di, acc[4 * q + 3] * di);
}

// Gather-reduce over CSR segment. 4 lanes per node, each lane owns a float4.
template <bool RELU>
__global__ void k_agg(const int* __restrict__ ptr, const int* __restrict__ rows_sorted,
                      const float* __restrict__ src, const int* __restrict__ cnt,
                      const float* __restrict__ b1, float* __restrict__ dst, int n) {
    int t = blockIdx.x * blockDim.x + threadIdx.x;
    int g = t >> 2;            // node
    if (g >= n) return;
    int q = (t & 3) << 2;      // float4 slot
    float4 acc = *reinterpret_cast<const float4*>(src + (size_t)g * HID + q);
    int s = ptr[g], e2 = ptr[g + 1];
    int k = s;
    for (; k + 1 < e2; k += 2) {
        int r0 = rows_sorted[k], r1 = rows_sorted[k + 1];
        float4 v0 = *reinterpret_cast<const float4*>(src + (size_t)r0 * HID + q);
        float4 v1 = *reinterpret_cast<const float4*>(src + (size_t)r1 * HID + q);
        acc.x += v0.x + v1.x; acc.y += v0.y + v1.y;
        acc.z += v0.z + v1.z; acc.w += v0.w + v1.w;
    }
    if (k < e2) {
        int r0 = rows_sorted[k];
        float4 v0 = *reinterpret_cast<const float4*>(src + (size_t)r0 * HID + q);
        acc.x += v0.x; acc.y += v0.y; acc.z += v0.z; acc.w += v0.w;
    }
    float d = rsqrtf((float)(cnt[g] + 1));
    float4 o;
    if (RELU) {
        float4 bb = *reinterpret_cast<const float4*>(b1 + q);
        o.x = d * fmaxf(fmaf(d, acc.x, bb.x), 0.f);
        o.y = d * fmaxf(fmaf(d, acc.y, bb.y), 0.f);
        o.z = d * fmaxf(fmaf(d, acc.z, bb.z), 0.f);
        o.w = d * fmaxf(fmaf(d, acc.w, bb.w), 0.f);
    } else {
        o.x = d * acc.x; o.y = d * acc.y; o.z = d * acc.z; o.w = d * acc.w;
    }
    *reinterpret_cast<float4*>(dst + (size_t)g * HID + q) = o;
}

// out = log_softmax(agg2 @ W2 + b2)
__global__ void k_final(const float* __restrict__ agg2, const float* __restrict__ W2,
                        const float* __restrict__ b2, float* __restrict__ out, int n) {
    int node = blockIdx.x * blockDim.x + threadIdx.x;
    if (node >= n) return;
    const float4* ar = reinterpret_cast<const float4*>(agg2 + (size_t)node * HID);
    float a[HID];
#pragma unroll
    for (int q = 0; q < 4; ++q) {
        float4 t = ar[q];
        a[4 * q] = t.x; a[4 * q + 1] = t.y; a[4 * q + 2] = t.z; a[4 * q + 3] = t.w;
    }
    float z[NCLS];
#pragma unroll
    for (int j = 0; j < NCLS; ++j) z[j] = b2[j];
#pragma unroll
    for (int i = 0; i < HID; ++i) {
        const float* w = W2 + (size_t)i * NCLS;
        float ai = a[i];
#pragma unroll
        for (int j = 0; j < NCLS; ++j) z[j] = fmaf(ai, w[j], z[j]);
    }
    float m = z[0];
#pragma unroll
    for (int j = 1; j < NCLS; ++j) m = fmaxf(m, z[j]);
    float s = 0.f;
#pragma unroll
    for (int j = 0; j < NCLS; ++j) s += __expf(z[j] - m);
    float ls = m + __logf(s);
    float* o = out + (size_t)node * NCLS;
#pragma unroll
    for (int q = 0; q < NCLS / 4; ++q)
        *reinterpret_cast<float4*>(o + 4 * q) =
            make_float4(z[4 * q] - ls, z[4 * q + 1] - ls, z[4 * q + 2] - ls, z[4 * q + 3] - ls);
}

extern "C" void kernel_launch(void* const* d_in, const int* in_sizes, int n_in,
                              void* d_out, int out_size, void* d_ws, size_t ws_size,
                              hipStream_t stream) {
    const float* x  = (const float*)d_in[0];
    const int*   ei = (const int*)d_in[1];
    const float* W1 = (const float*)d_in[2];
    const float* b1 = (const float*)d_in[3];
    const float* W2 = (const float*)d_in[4];
    const float* b2 = (const float*)d_in[5];
    float* out = (float*)d_out;

    const int N = in_sizes[0] / F_IN;   // 100000
    const int E = in_sizes[1] / 2;      // 3200000
    const int* row = ei;        // source nodes
    const int* col = ei + E;    // target nodes
    const int NBUCK = (N + BNODES - 1) >> BSH2;   // 391

    // workspace: rows_raw/lcol (dead after k_csr) alias yp/hp
    char* w = (char*)d_ws;
    int*   cnt    = (int*)w;   w += (size_t)N * 4;
    int*   bcnt   = (int*)w;   w += (size_t)NBMAX * 4;
    int*   bstart = (int*)w;   w += (size_t)(NBMAX + 1) * 4;
    int*   bcur   = (int*)w;   w += (size_t)NBMAX * 4;
    int*   ptr    = (int*)w;   w += (size_t)(N + 1) * 4;
    int*   rows_sorted = (int*)w; w += (size_t)E * 4;
    char*  uni    = w;         // union: rows_raw(E*4)+lcol(E) vs yp+hp (32N floats)
    int*   rows_raw = (int*)uni;
    unsigned char* lcol = (unsigned char*)(uni + (size_t)E * 4);
    float* yp     = (float*)uni;
    float* hp     = yp + (size_t)N * HID;
    float* agg2   = yp;        // alias (yp dead after layer-1 agg)

    const int B = 256;
    const int NEB = (E + EPB - 1) / EPB;   // 391 edge blocks
    k_zero_i<<<(NBMAX + B - 1) / B, B, 0, stream>>>(bcnt, NBMAX);
    k_bhist <<<NEB, B, 0, stream>>>(col, bcnt, E);
    k_bscan <<<1, 512, 0, stream>>>(bcnt, bstart, bcur, NBUCK);
    k_bucket<<<NEB, B, 0, stream>>>(row, col, bcur, rows_raw, lcol, E);
    k_csr   <<<NBUCK, 512, 0, stream>>>(cnt, bstart, rows_raw, lcol, ptr, rows_sorted, N, NBUCK);
    k_gemm1 <<<(N + B - 1) / B, B, 0, stream>>>(x, W1, cnt, yp, N);
    k_agg<true> <<<((N * 4) + B - 1) / B, B, 0, stream>>>(ptr, rows_sorted, yp, cnt, b1, hp, N);
    k_agg<false><<<((N * 4) + B - 1) / B, B, 0, stream>>>(ptr, rows_sorted, hp, cnt, nullptr, agg2, N);
    k_final <<<(N + B - 1) / B, B, 0, stream>>>(agg2, W2, b2, out, N);
}

// Round 8
// 367.075 us; speedup vs baseline: 2.6714x; 1.2047x over previous
//
#include <hip/hip_runtime.h>

#define F_IN 512
#define HID  16
#define NCLS 40
#define KSPL 2
#define KH   (F_IN / KSPL)   // 256
#define BSH2 8            // 256 nodes per bucket
#define BNODES 256
#define NBMAX 512         // >= nbuckets = 391
#define EPB 8192          // edges per k_bucket/k_bhist block
#define CAP 12288         // LDS row buffer capacity (mean 8184, sigma~90)

__global__ void k_zero_i(int* __restrict__ p, int n) {
    int i = blockIdx.x * blockDim.x + threadIdx.x;
    if (i < n) p[i] = 0;
}

// per-bucket histogram via LDS: ~391 global atomics per block instead of 8192
__global__ void k_bhist(const int* __restrict__ col, int* __restrict__ bcnt, int ne) {
    __shared__ int lh[NBMAX];
    int t = threadIdx.x;
    for (int i = t; i < NBMAX; i += 256) lh[i] = 0;
    __syncthreads();
    int base = blockIdx.x * EPB;
    int end = min(ne, base + EPB);
    int e = base + t * 4;
    for (; e + 3 < end; e += 1024) {
        int4 c = *reinterpret_cast<const int4*>(col + e);
        atomicAdd(&lh[c.x >> BSH2], 1);
        atomicAdd(&lh[c.y >> BSH2], 1);
        atomicAdd(&lh[c.z >> BSH2], 1);
        atomicAdd(&lh[c.w >> BSH2], 1);
    }
    for (; e < end; ++e) atomicAdd(&lh[col[e] >> BSH2], 1);
    __syncthreads();
    for (int i = t; i < NBMAX; i += 256)
        if (lh[i] > 0) atomicAdd(&bcnt[i], lh[i]);
}

// single tiny block: exclusive scan of bucket counts -> bstart (+ total), bcur copy
__global__ void k_bscan(const int* __restrict__ bcnt, int* __restrict__ bstart,
                        int* __restrict__ bcur, int nb) {
    __shared__ int sh[512];
    int t = threadIdx.x;
    int v = (t < nb) ? bcnt[t] : 0;
    sh[t] = v;
    __syncthreads();
    for (int off = 1; off < 512; off <<= 1) {
        int u = (t >= off) ? sh[t - off] : 0;
        __syncthreads();
        sh[t] += u;
        __syncthreads();
    }
    if (t < nb) {
        int ex = sh[t] - v;
        bstart[t] = ex;
        bcur[t] = ex;
    }
    if (t == nb - 1) bstart[nb] = sh[t];
}

// two-pass bucket partition: count -> allocate -> write rows_raw (int) + lcol (uchar)
__global__ void k_bucket(const int* __restrict__ row, const int* __restrict__ col,
                         int* __restrict__ bcur, int* __restrict__ rows_raw,
                         unsigned char* __restrict__ lcol, int ne) {
    __shared__ int lhist[NBMAX];
    __shared__ int gbase[NBMAX];
    __shared__ int lcur[NBMAX];
    int t = threadIdx.x;
    for (int i = t; i < NBMAX; i += 256) { lhist[i] = 0; lcur[i] = 0; }
    __syncthreads();
    int base = blockIdx.x * EPB;
    int end = min(ne, base + EPB);
    for (int e = base + t; e < end; e += 256)
        atomicAdd(&lhist[col[e] >> BSH2], 1);
    __syncthreads();
    for (int i = t; i < NBMAX; i += 256)
        if (lhist[i] > 0) gbase[i] = atomicAdd(&bcur[i], lhist[i]);
    __syncthreads();
    for (int e = base + t; e < end; e += 256) {
        int r = row[e], c = col[e];
        int gb = c >> BSH2;
        int rk = atomicAdd(&lcur[gb], 1);
        int p = gbase[gb] + rk;
        rows_raw[p] = r;
        lcol[p] = (unsigned char)(c & (BNODES - 1));
    }
}

// per-bucket CSR finalize: LDS count -> cnt + ptr; LDS-scatter -> coalesced rows_sorted
__global__ __launch_bounds__(512) void k_csr(
    int* __restrict__ cnt, const int* __restrict__ bstart,
    const int* __restrict__ rows_raw, const unsigned char* __restrict__ lcol,
    int* __restrict__ ptr, int* __restrict__ rows_sorted, int n, int nb) {
    __shared__ int sh[BNODES];
    __shared__ int lcur[BNODES];
    __shared__ int lrows[CAP];
    int b = blockIdx.x, t = threadIdx.x;
    int c0 = b << BSH2;
    int nloc = min(BNODES, n - c0);
    int s = bstart[b], e = bstart[b + 1];
    int m = e - s;
    if (t < BNODES) sh[t] = 0;
    __syncthreads();
    for (int k = t; k < m; k += 512) atomicAdd(&sh[lcol[s + k]], 1);
    __syncthreads();
    int own = (t < BNODES) ? sh[t] : 0;
    if (t < nloc) cnt[c0 + t] = own;
    for (int off = 1; off < BNODES; off <<= 1) {
        int v = (t >= off && t < BNODES) ? sh[t - off] : 0;
        __syncthreads();
        if (t < BNODES) sh[t] += v;
        __syncthreads();
    }
    if (t < nloc) {
        int ex = sh[t] - own;
        ptr[c0 + t] = s + ex;
        lcur[t] = ex;
    }
    if (b == nb - 1 && t == 0) ptr[n] = e;
    __syncthreads();
    if (m <= CAP) {
        for (int k = t; k < m; k += 512) {
            int pos = atomicAdd(&lcur[lcol[s + k]], 1);
            lrows[pos] = rows_raw[s + k];
        }
        __syncthreads();
        for (int k = t; k < m; k += 512) rows_sorted[s + k] = lrows[k];
    } else {
        for (int k = t; k < m; k += 512) {
            int pos = atomicAdd(&lcur[lcol[s + k]], 1);
            rows_sorted[s + pos] = rows_raw[s + k];
        }
    }
}

// half-K GEMM: out[node][j] = sum over k in [half*KH, half*KH+KH) x[node][k]*W1[k][j]
// 4 float4 loads batched per 16-k step; W1 stays wave-uniform (SGPR broadcast)
#define STEP(av, kk) \
    _Pragma("unroll") for (int j = 0; j < HID; ++j) acc[j] = fmaf(av, w[(kk) * HID + j], acc[j]);

__global__ __launch_bounds__(256) void k_gemm1(
    const float* __restrict__ x, const float* __restrict__ W1,
    float* __restrict__ ypA, float* __restrict__ ypB, int n) {
    int node = blockIdx.x * blockDim.x + threadIdx.x;
    if (node >= n) return;
    int half = blockIdx.y;
    const float* xr = x + (size_t)node * F_IN + half * KH;
    const float* Wb = W1 + (size_t)half * KH * HID;
    float acc[HID];
#pragma unroll
    for (int j = 0; j < HID; ++j) acc[j] = 0.f;
    for (int k = 0; k < KH; k += 16) {
        const float4* xv = reinterpret_cast<const float4*>(xr + k);
        float4 a0 = xv[0], a1 = xv[1], a2 = xv[2], a3 = xv[3];
        const float* w = Wb + (size_t)k * HID;
        STEP(a0.x, 0)  STEP(a0.y, 1)  STEP(a0.z, 2)  STEP(a0.w, 3)
        STEP(a1.x, 4)  STEP(a1.y, 5)  STEP(a1.z, 6)  STEP(a1.w, 7)
        STEP(a2.x, 8)  STEP(a2.y, 9)  STEP(a2.z, 10) STEP(a2.w, 11)
        STEP(a3.x, 12) STEP(a3.y, 13) STEP(a3.z, 14) STEP(a3.w, 15)
    }
    float* o = (half == 0 ? ypA : ypB) + (size_t)node * HID;
    float4* o4 = reinterpret_cast<float4*>(o);
#pragma unroll
    for (int q = 0; q < 4; ++q)
        o4[q] = make_float4(acc[4 * q], acc[4 * q + 1], acc[4 * q + 2], acc[4 * q + 3]);
}

// yp = dinv * (ypA + ypB)   (dinv prescale folded in)
__global__ void k_comb(const float* __restrict__ A, const float* __restrict__ B,
                       const int* __restrict__ cnt, float* __restrict__ yp, int n) {
    int i = blockIdx.x * blockDim.x + threadIdx.x;   // one float4 per thread
    if (i >= n * 4) return;
    int node = i >> 2;
    float di = rsqrtf((float)(cnt[node] + 1));
    float4 a = reinterpret_cast<const float4*>(A)[i];
    float4 b = reinterpret_cast<const float4*>(B)[i];
    reinterpret_cast<float4*>(yp)[i] =
        make_float4(di * (a.x + b.x), di * (a.y + b.y), di * (a.z + b.z), di * (a.w + b.w));
}

// Gather-reduce over CSR segment. 4 lanes per node, each lane owns a float4.
template <bool RELU>
__global__ void k_agg(const int* __restrict__ ptr, const int* __restrict__ rows_sorted,
                      const float* __restrict__ src, const int* __restrict__ cnt,
                      const float* __restrict__ b1, float* __restrict__ dst, int n) {
    int t = blockIdx.x * blockDim.x + threadIdx.x;
    int g = t >> 2;
    if (g >= n) return;
    int q = (t & 3) << 2;
    float4 acc = *reinterpret_cast<const float4*>(src + (size_t)g * HID + q);
    int s = ptr[g], e2 = ptr[g + 1];
    int k = s;
    for (; k + 1 < e2; k += 2) {
        int r0 = rows_sorted[k], r1 = rows_sorted[k + 1];
        float4 v0 = *reinterpret_cast<const float4*>(src + (size_t)r0 * HID + q);
        float4 v1 = *reinterpret_cast<const float4*>(src + (size_t)r1 * HID + q);
        acc.x += v0.x + v1.x; acc.y += v0.y + v1.y;
        acc.z += v0.z + v1.z; acc.w += v0.w + v1.w;
    }
    if (k < e2) {
        int r0 = rows_sorted[k];
        float4 v0 = *reinterpret_cast<const float4*>(src + (size_t)r0 * HID + q);
        acc.x += v0.x; acc.y += v0.y; acc.z += v0.z; acc.w += v0.w;
    }
    float d = rsqrtf((float)(cnt[g] + 1));
    float4 o;
    if (RELU) {
        float4 bb = *reinterpret_cast<const float4*>(b1 + q);
        o.x = d * fmaxf(fmaf(d, acc.x, bb.x), 0.f);
        o.y = d * fmaxf(fmaf(d, acc.y, bb.y), 0.f);
        o.z = d * fmaxf(fmaf(d, acc.z, bb.z), 0.f);
        o.w = d * fmaxf(fmaf(d, acc.w, bb.w), 0.f);
    } else {
        o.x = d * acc.x; o.y = d * acc.y; o.z = d * acc.z; o.w = d * acc.w;
    }
    *reinterpret_cast<float4*>(dst + (size_t)g * HID + q) = o;
}

// out = log_softmax(agg2 @ W2 + b2)
__global__ void k_final(const float* __restrict__ agg2, const float* __restrict__ W2,
                        const float* __restrict__ b2, float* __restrict__ out, int n) {
    int node = blockIdx.x * blockDim.x + threadIdx.x;
    if (node >= n) return;
    const float4* ar = reinterpret_cast<const float4*>(agg2 + (size_t)node * HID);
    float a[HID];
#pragma unroll
    for (int q = 0; q < 4; ++q) {
        float4 t = ar[q];
        a[4 * q] = t.x; a[4 * q + 1] = t.y; a[4 * q + 2] = t.z; a[4 * q + 3] = t.w;
    }
    float z[NCLS];
#pragma unroll
    for (int j = 0; j < NCLS; ++j) z[j] = b2[j];
#pragma unroll
    for (int i = 0; i < HID; ++i) {
        const float* w = W2 + (size_t)i * NCLS;
        float ai = a[i];
#pragma unroll
        for (int j = 0; j < NCLS; ++j) z[j] = fmaf(ai, w[j], z[j]);
    }
    float m = z[0];
#pragma unroll
    for (int j = 1; j < NCLS; ++j) m = fmaxf(m, z[j]);
    float s = 0.f;
#pragma unroll
    for (int j = 0; j < NCLS; ++j) s += __expf(z[j] - m);
    float ls = m + __logf(s);
    float* o = out + (size_t)node * NCLS;
#pragma unroll
    for (int q = 0; q < NCLS / 4; ++q)
        *reinterpret_cast<float4*>(o + 4 * q) =
            make_float4(z[4 * q] - ls, z[4 * q + 1] - ls, z[4 * q + 2] - ls, z[4 * q + 3] - ls);
}

extern "C" void kernel_launch(void* const* d_in, const int* in_sizes, int n_in,
                              void* d_out, int out_size, void* d_ws, size_t ws_size,
                              hipStream_t stream) {
    const float* x  = (const float*)d_in[0];
    const int*   ei = (const int*)d_in[1];
    const float* W1 = (const float*)d_in[2];
    const float* b1 = (const float*)d_in[3];
    const float* W2 = (const float*)d_in[4];
    const float* b2 = (const float*)d_in[5];
    float* out = (float*)d_out;

    const int N = in_sizes[0] / F_IN;   // 100000
    const int E = in_sizes[1] / 2;      // 3200000
    const int* row = ei;
    const int* col = ei + E;
    const int NBUCK = (N + BNODES - 1) >> BSH2;   // 391

    char* w = (char*)d_ws;
    int*   cnt    = (int*)w;   w += (size_t)N * 4;
    int*   bcnt   = (int*)w;   w += (size_t)NBMAX * 4;
    int*   bstart = (int*)w;   w += (size_t)(NBMAX + 1) * 4;
    int*   bcur   = (int*)w;   w += (size_t)NBMAX * 4;
    int*   ptr    = (int*)w;   w += (size_t)(N + 1) * 4;
    int*   rows_sorted = (int*)w; w += (size_t)E * 4;
    int*   rows_raw = (int*)w; w += (size_t)E * 4;
    unsigned char* lcol = (unsigned char*)w; w += (size_t)E;
    float* ypA    = (float*)w; w += (size_t)N * HID * 4;
    float* ypB    = (float*)w; w += (size_t)N * HID * 4;
    float* yp     = (float*)w; w += (size_t)N * HID * 4;
    float* hp     = (float*)w; w += (size_t)N * HID * 4;
    float* agg2   = yp;        // alias (yp dead after layer-1 agg)

    const int B = 256;
    const int NEB = (E + EPB - 1) / EPB;   // 391 edge blocks
    k_zero_i<<<(NBMAX + B - 1) / B, B, 0, stream>>>(bcnt, NBMAX);
    k_bhist <<<NEB, B, 0, stream>>>(col, bcnt, E);
    k_bscan <<<1, 512, 0, stream>>>(bcnt, bstart, bcur, NBUCK);
    k_bucket<<<NEB, B, 0, stream>>>(row, col, bcur, rows_raw, lcol, E);
    k_csr   <<<NBUCK, 512, 0, stream>>>(cnt, bstart, rows_raw, lcol, ptr, rows_sorted, N, NBUCK);
    k_gemm1 <<<dim3((N + B - 1) / B, KSPL), B, 0, stream>>>(x, W1, ypA, ypB, N);
    k_comb  <<<((N * 4) + B - 1) / B, B, 0, stream>>>(ypA, ypB, cnt, yp, N);
    k_agg<true> <<<((N * 4) + B - 1) / B, B, 0, stream>>>(ptr, rows_sorted, yp, cnt, b1, hp, N);
    k_agg<false><<<((N * 4) + B - 1) / B, B, 0, stream>>>(ptr, rows_sorted, hp, cnt, nullptr, agg2, N);
    k_final <<<(N + B - 1) / B, B, 0, stream>>>(agg2, W2, b2, out, N);
}

// Round 9
// 294.411 us; speedup vs baseline: 3.3307x; 1.2468x over previous
//
#include <hip/hip_runtime.h>

#define F_IN 512
#define HID  16
#define NCLS 40
#define KSPL 2
#define KH   (F_IN / KSPL)   // 256
#define BSH2 8            // 256 nodes per bucket
#define BNODES 256
#define NBMAX 512         // >= nbuckets = 391
#define EPB 8192          // edges per k_bucket/k_bhist block
#define CAP 12288         // LDS row buffer capacity (mean 8184, sigma~90)

__global__ void k_zero_i(int* __restrict__ p, int n) {
    int i = blockIdx.x * blockDim.x + threadIdx.x;
    if (i < n) p[i] = 0;
}

// per-bucket histogram via LDS: ~391 global atomics per block instead of 8192
__global__ void k_bhist(const int* __restrict__ col, int* __restrict__ bcnt, int ne) {
    __shared__ int lh[NBMAX];
    int t = threadIdx.x;
    for (int i = t; i < NBMAX; i += 256) lh[i] = 0;
    __syncthreads();
    int base = blockIdx.x * EPB;
    int end = min(ne, base + EPB);
    int e = base + t * 4;
    for (; e + 3 < end; e += 1024) {
        int4 c = *reinterpret_cast<const int4*>(col + e);
        atomicAdd(&lh[c.x >> BSH2], 1);
        atomicAdd(&lh[c.y >> BSH2], 1);
        atomicAdd(&lh[c.z >> BSH2], 1);
        atomicAdd(&lh[c.w >> BSH2], 1);
    }
    for (; e < end; ++e) atomicAdd(&lh[col[e] >> BSH2], 1);
    __syncthreads();
    for (int i = t; i < NBMAX; i += 256)
        if (lh[i] > 0) atomicAdd(&bcnt[i], lh[i]);
}

// single tiny block: exclusive scan of bucket counts -> bstart (+ total), bcur copy
__global__ void k_bscan(const int* __restrict__ bcnt, int* __restrict__ bstart,
                        int* __restrict__ bcur, int nb) {
    __shared__ int sh[512];
    int t = threadIdx.x;
    int v = (t < nb) ? bcnt[t] : 0;
    sh[t] = v;
    __syncthreads();
    for (int off = 1; off < 512; off <<= 1) {
        int u = (t >= off) ? sh[t - off] : 0;
        __syncthreads();
        sh[t] += u;
        __syncthreads();
    }
    if (t < nb) {
        int ex = sh[t] - v;
        bstart[t] = ex;
        bcur[t] = ex;
    }
    if (t == nb - 1) bstart[nb] = sh[t];
}

// 3-phase LDS counting sort per 8192-edge block:
// hist -> alloc(global)+scan(local) -> LDS scatter -> linear per-bucket copy-out
__global__ __launch_bounds__(512) void k_bucket(
    const int* __restrict__ row, const int* __restrict__ col,
    int* __restrict__ bcur, int* __restrict__ packed, int ne, int nb) {
    __shared__ int lhist[NBMAX];
    __shared__ int lbase[NBMAX];   // block-local exclusive scan
    __shared__ int gbase[NBMAX];   // global window start for this block
    __shared__ int lcur[NBMAX];
    __shared__ int buf[EPB];       // packed (lc<<24 | row), bucket-ordered
    int t = threadIdx.x;
    for (int i = t; i < NBMAX; i += 512) { lhist[i] = 0; lcur[i] = 0; }
    __syncthreads();
    int base = blockIdx.x * EPB;
    int end = min(ne, base + EPB);
    // phase 1: histogram
    for (int e = base + t; e < end; e += 512)
        atomicAdd(&lhist[col[e] >> BSH2], 1);
    __syncthreads();
    // global alloc + local scan (thread t owns entry t; NBMAX == 512 == blockDim)
    int own = lhist[t];
    if (own > 0) gbase[t] = atomicAdd(&bcur[t], own);
    lbase[t] = own;
    __syncthreads();
    for (int off = 1; off < 512; off <<= 1) {
        int v = (t >= off) ? lbase[t - off] : 0;
        __syncthreads();
        lbase[t] += v;
        __syncthreads();
    }
    // convert inclusive -> exclusive in place
    int ex = lbase[t] - own;
    __syncthreads();
    lbase[t] = ex;
    __syncthreads();
    // phase 2: scatter into LDS (bucket-ordered)
    for (int e = base + t; e < end; e += 512) {
        int r = row[e], c = col[e];
        int gb = c >> BSH2;
        int rk = atomicAdd(&lcur[gb], 1);
        buf[lbase[gb] + rk] = r | ((c & (BNODES - 1)) << 24);
    }
    __syncthreads();
    // phase 3: per-wave per-bucket linear copy-out (coalesced runs)
    int wv = t >> 6, lane = t & 63;
    for (int b = wv; b < nb; b += 8) {
        int cntb = lhist[b];
        int lb = lbase[b], gb2 = gbase[b];
        for (int k = lane; k < cntb; k += 64)
            packed[gb2 + k] = buf[lb + k];
    }
}

// per-bucket CSR finalize: LDS count -> cnt + ptr; LDS-scatter -> coalesced rows_sorted
__global__ __launch_bounds__(512) void k_csr(
    int* __restrict__ cnt, const int* __restrict__ bstart,
    const int* __restrict__ packed, int* __restrict__ ptr,
    int* __restrict__ rows_sorted, int n, int nb) {
    __shared__ int sh[BNODES];
    __shared__ int lcur[BNODES];
    __shared__ int lrows[CAP];
    int b = blockIdx.x, t = threadIdx.x;
    int c0 = b << BSH2;
    int nloc = min(BNODES, n - c0);
    int s = bstart[b], e = bstart[b + 1];
    int m = e - s;
    if (t < BNODES) sh[t] = 0;
    __syncthreads();
    for (int k = t; k < m; k += 512)
        atomicAdd(&sh[((unsigned)packed[s + k]) >> 24], 1);
    __syncthreads();
    int own = (t < BNODES) ? sh[t] : 0;
    if (t < nloc) cnt[c0 + t] = own;
    for (int off = 1; off < BNODES; off <<= 1) {
        int v = (t >= off && t < BNODES) ? sh[t - off] : 0;
        __syncthreads();
        if (t < BNODES) sh[t] += v;
        __syncthreads();
    }
    if (t < nloc) {
        int ex = sh[t] - own;
        ptr[c0 + t] = s + ex;
        lcur[t] = ex;
    }
    if (b == nb - 1 && t == 0) ptr[n] = e;
    __syncthreads();
    if (m <= CAP) {
        for (int k = t; k < m; k += 512) {
            int p = packed[s + k];
            int pos = atomicAdd(&lcur[((unsigned)p) >> 24], 1);
            lrows[pos] = p & 0xFFFFFF;
        }
        __syncthreads();
        for (int k = t; k < m; k += 512) rows_sorted[s + k] = lrows[k];
    } else {
        for (int k = t; k < m; k += 512) {
            int p = packed[s + k];
            int pos = atomicAdd(&lcur[((unsigned)p) >> 24], 1);
            rows_sorted[s + pos] = p & 0xFFFFFF;
        }
    }
}

// half-K GEMM: out[node][j] = sum over k in [half*KH, half*KH+KH) x[node][k]*W1[k][j]
#define STEP(av, kk) \
    _Pragma("unroll") for (int j = 0; j < HID; ++j) acc[j] = fmaf(av, w[(kk) * HID + j], acc[j]);

__global__ __launch_bounds__(256) void k_gemm1(
    const float* __restrict__ x, const float* __restrict__ W1,
    float* __restrict__ ypA, float* __restrict__ ypB, int n) {
    int node = blockIdx.x * blockDim.x + threadIdx.x;
    if (node >= n) return;
    int half = blockIdx.y;
    const float* xr = x + (size_t)node * F_IN + half * KH;
    const float* Wb = W1 + (size_t)half * KH * HID;
    float acc[HID];
#pragma unroll
    for (int j = 0; j < HID; ++j) acc[j] = 0.f;
    for (int k = 0; k < KH; k += 16) {
        const float4* xv = reinterpret_cast<const float4*>(xr + k);
        float4 a0 = xv[0], a1 = xv[1], a2 = xv[2], a3 = xv[3];
        const float* w = Wb + (size_t)k * HID;
        STEP(a0.x, 0)  STEP(a0.y, 1)  STEP(a0.z, 2)  STEP(a0.w, 3)
        STEP(a1.x, 4)  STEP(a1.y, 5)  STEP(a1.z, 6)  STEP(a1.w, 7)
        STEP(a2.x, 8)  STEP(a2.y, 9)  STEP(a2.z, 10) STEP(a2.w, 11)
        STEP(a3.x, 12) STEP(a3.y, 13) STEP(a3.z, 14) STEP(a3.w, 15)
    }
    float* o = (half == 0 ? ypA : ypB) + (size_t)node * HID;
    float4* o4 = reinterpret_cast<float4*>(o);
#pragma unroll
    for (int q = 0; q < 4; ++q)
        o4[q] = make_float4(acc[4 * q], acc[4 * q + 1], acc[4 * q + 2], acc[4 * q + 3]);
}

// yp = dinv * (ypA + ypB)
__global__ void k_comb(const float* __restrict__ A, const float* __restrict__ B,
                       const int* __restrict__ cnt, float* __restrict__ yp, int n) {
    int i = blockIdx.x * blockDim.x + threadIdx.x;
    if (i >= n * 4) return;
    int node = i >> 2;
    float di = rsqrtf((float)(cnt[node] + 1));
    float4 a = reinterpret_cast<const float4*>(A)[i];
    float4 b = reinterpret_cast<const float4*>(B)[i];
    reinterpret_cast<float4*>(yp)[i] =
        make_float4(di * (a.x + b.x), di * (a.y + b.y), di * (a.z + b.z), di * (a.w + b.w));
}

// Gather-reduce over CSR segment. 4 lanes per node, each lane owns a float4.
template <bool RELU>
__global__ void k_agg(const int* __restrict__ ptr, const int* __restrict__ rows_sorted,
                      const float* __restrict__ src, const int* __restrict__ cnt,
                      const float* __restrict__ b1, float* __restrict__ dst, int n) {
    int t = blockIdx.x * blockDim.x + threadIdx.x;
    int g = t >> 2;
    if (g >= n) return;
    int q = (t & 3) << 2;
    float4 acc = *reinterpret_cast<const float4*>(src + (size_t)g * HID + q);
    int s = ptr[g], e2 = ptr[g + 1];
    int k = s;
    for (; k + 1 < e2; k += 2) {
        int r0 = rows_sorted[k], r1 = rows_sorted[k + 1];
        float4 v0 = *reinterpret_cast<const float4*>(src + (size_t)r0 * HID + q);
        float4 v1 = *reinterpret_cast<const float4*>(src + (size_t)r1 * HID + q);
        acc.x += v0.x + v1.x; acc.y += v0.y + v1.y;
        acc.z += v0.z + v1.z; acc.w += v0.w + v1.w;
    }
    if (k < e2) {
        int r0 = rows_sorted[k];
        float4 v0 = *reinterpret_cast<const float4*>(src + (size_t)r0 * HID + q);
        acc.x += v0.x; acc.y += v0.y; acc.z += v0.z; acc.w += v0.w;
    }
    float d = rsqrtf((float)(cnt[g] + 1));
    float4 o;
    if (RELU) {
        float4 bb = *reinterpret_cast<const float4*>(b1 + q);
        o.x = d * fmaxf(fmaf(d, acc.x, bb.x), 0.f);
        o.y = d * fmaxf(fmaf(d, acc.y, bb.y), 0.f);
        o.z = d * fmaxf(fmaf(d, acc.z, bb.z), 0.f);
        o.w = d * fmaxf(fmaf(d, acc.w, bb.w), 0.f);
    } else {
        o.x = d * acc.x; o.y = d * acc.y; o.z = d * acc.z; o.w = d * acc.w;
    }
    *reinterpret_cast<float4*>(dst + (size_t)g * HID + q) = o;
}

// out = log_softmax(agg2 @ W2 + b2)
__global__ void k_final(const float* __restrict__ agg2, const float* __restrict__ W2,
                        const float* __restrict__ b2, float* __restrict__ out, int n) {
    int node = blockIdx.x * blockDim.x + threadIdx.x;
    if (node >= n) return;
    const float4* ar = reinterpret_cast<const float4*>(agg2 + (size_t)node * HID);
    float a[HID];
#pragma unroll
    for (int q = 0; q < 4; ++q) {
        float4 t = ar[q];
        a[4 * q] = t.x; a[4 * q + 1] = t.y; a[4 * q + 2] = t.z; a[4 * q + 3] = t.w;
    }
    float z[NCLS];
#pragma unroll
    for (int j = 0; j < NCLS; ++j) z[j] = b2[j];
#pragma unroll
    for (int i = 0; i < HID; ++i) {
        const float* w = W2 + (size_t)i * NCLS;
        float ai = a[i];
#pragma unroll
        for (int j = 0; j < NCLS; ++j) z[j] = fmaf(ai, w[j], z[j]);
    }
    float m = z[0];
#pragma unroll
    for (int j = 1; j < NCLS; ++j) m = fmaxf(m, z[j]);
    float s = 0.f;
#pragma unroll
    for (int j = 0; j < NCLS; ++j) s += __expf(z[j] - m);
    float ls = m + __logf(s);
    float* o = out + (size_t)node * NCLS;
#pragma unroll
    for (int q = 0; q < NCLS / 4; ++q)
        *reinterpret_cast<float4*>(o + 4 * q) =
            make_float4(z[4 * q] - ls, z[4 * q + 1] - ls, z[4 * q + 2] - ls, z[4 * q + 3] - ls);
}

extern "C" void kernel_launch(void* const* d_in, const int* in_sizes, int n_in,
                              void* d_out, int out_size, void* d_ws, size_t ws_size,
                              hipStream_t stream) {
    const float* x  = (const float*)d_in[0];
    const int*   ei = (const int*)d_in[1];
    const float* W1 = (const float*)d_in[2];
    const float* b1 = (const float*)d_in[3];
    const float* W2 = (const float*)d_in[4];
    const float* b2 = (const float*)d_in[5];
    float* out = (float*)d_out;

    const int N = in_sizes[0] / F_IN;   // 100000
    const int E = in_sizes[1] / 2;      // 3200000
    const int* row = ei;
    const int* col = ei + E;
    const int NBUCK = (N + BNODES - 1) >> BSH2;   // 391

    char* w = (char*)d_ws;
    int*   cnt    = (int*)w;   w += (size_t)N * 4;
    int*   bcnt   = (int*)w;   w += (size_t)NBMAX * 4;
    int*   bstart = (int*)w;   w += (size_t)(NBMAX + 1) * 4;
    int*   bcur   = (int*)w;   w += (size_t)NBMAX * 4;
    int*   ptr    = (int*)w;   w += (size_t)(N + 1) * 4;
    int*   rows_sorted = (int*)w; w += (size_t)E * 4;
    int*   packed = (int*)w;   w += (size_t)E * 4;
    float* ypA    = (float*)w; w += (size_t)N * HID * 4;
    float* ypB    = (float*)w; w += (size_t)N * HID * 4;
    float* yp     = (float*)w; w += (size_t)N * HID * 4;
    float* hp     = (float*)w; w += (size_t)N * HID * 4;
    float* agg2   = yp;        // alias (yp dead after layer-1 agg)

    const int B = 256;
    const int NEB = (E + EPB - 1) / EPB;   // 391 edge blocks
    k_zero_i<<<(NBMAX + B - 1) / B, B, 0, stream>>>(bcnt, NBMAX);
    k_bhist <<<NEB, B, 0, stream>>>(col, bcnt, E);
    k_bscan <<<1, 512, 0, stream>>>(bcnt, bstart, bcur, NBUCK);
    k_bucket<<<NEB, 512, 0, stream>>>(row, col, bcur, packed, E, NBUCK);
    k_csr   <<<NBUCK, 512, 0, stream>>>(cnt, bstart, packed, ptr, rows_sorted, N, NBUCK);
    k_gemm1 <<<dim3((N + B - 1) / B, KSPL), B, 0, stream>>>(x, W1, ypA, ypB, N);
    k_comb  <<<((N * 4) + B - 1) / B, B, 0, stream>>>(ypA, ypB, cnt, yp, N);
    k_agg<true> <<<((N * 4) + B - 1) / B, B, 0, stream>>>(ptr, rows_sorted, yp, cnt, b1, hp, N);
    k_agg<false><<<((N * 4) + B - 1) / B, B, 0, stream>>>(ptr, rows_sorted, hp, cnt, nullptr, agg2, N);
    k_final <<<(N + B - 1) / B, B, 0, stream>>>(agg2, W2, b2, out, N);
}

// Round 10
// 273.659 us; speedup vs baseline: 3.5833x; 1.0758x over previous
//
#include <hip/hip_runtime.h>

#define F_IN 512
#define HID  16
#define NCLS 40
#define KSPL 4
#define KH   (F_IN / KSPL)   // 128
#define BSH2 8            // 256 nodes per bucket
#define BNODES 256
#define NBMAX 512         // >= nbuckets = 391
#define EPB 8192          // edges per k_bucket/k_bhist block
#define CAP 12288         // LDS row buffer capacity (mean 8184, sigma~90)

__global__ void k_zero_i(int* __restrict__ p, int n) {
    int i = blockIdx.x * blockDim.x + threadIdx.x;
    if (i < n) p[i] = 0;
}

// per-bucket histogram via LDS: ~391 global atomics per block instead of 8192
__global__ void k_bhist(const int* __restrict__ col, int* __restrict__ bcnt, int ne) {
    __shared__ int lh[NBMAX];
    int t = threadIdx.x;
    for (int i = t; i < NBMAX; i += 256) lh[i] = 0;
    __syncthreads();
    int base = blockIdx.x * EPB;
    int end = min(ne, base + EPB);
    int e = base + t * 4;
    for (; e + 3 < end; e += 1024) {
        int4 c = *reinterpret_cast<const int4*>(col + e);
        atomicAdd(&lh[c.x >> BSH2], 1);
        atomicAdd(&lh[c.y >> BSH2], 1);
        atomicAdd(&lh[c.z >> BSH2], 1);
        atomicAdd(&lh[c.w >> BSH2], 1);
    }
    for (; e < end; ++e) atomicAdd(&lh[col[e] >> BSH2], 1);
    __syncthreads();
    for (int i = t; i < NBMAX; i += 256)
        if (lh[i] > 0) atomicAdd(&bcnt[i], lh[i]);
}

// single tiny block: exclusive scan of bucket counts -> bstart (+ total), bcur copy
__global__ void k_bscan(const int* __restrict__ bcnt, int* __restrict__ bstart,
                        int* __restrict__ bcur, int nb) {
    __shared__ int sh[512];
    int t = threadIdx.x;
    int v = (t < nb) ? bcnt[t] : 0;
    sh[t] = v;
    __syncthreads();
    for (int off = 1; off < 512; off <<= 1) {
        int u = (t >= off) ? sh[t - off] : 0;
        __syncthreads();
        sh[t] += u;
        __syncthreads();
    }
    if (t < nb) {
        int ex = sh[t] - v;
        bstart[t] = ex;
        bcur[t] = ex;
    }
    if (t == nb - 1) bstart[nb] = sh[t];
}

// LDS counting sort per 8192-edge block; flat coalesced copy-out via bucket-id array
__global__ __launch_bounds__(512) void k_bucket(
    const int* __restrict__ row, const int* __restrict__ col,
    int* __restrict__ bcur, int* __restrict__ packed, int ne) {
    __shared__ int lhist[NBMAX];
    __shared__ int lbase[NBMAX];   // block-local exclusive scan
    __shared__ int gbase[NBMAX];   // global window start for this block
    __shared__ int lcur[NBMAX];
    __shared__ int buf[EPB];       // packed (lc<<24 | row), bucket-ordered
    __shared__ unsigned short bof[EPB];  // bucket id per slot
    int t = threadIdx.x;
    lhist[t] = 0; lcur[t] = 0;     // NBMAX == 512 == blockDim
    __syncthreads();
    int base = blockIdx.x * EPB;
    int end = min(ne, base + EPB);
    // phase 1: histogram
    for (int e = base + t; e < end; e += 512)
        atomicAdd(&lhist[col[e] >> BSH2], 1);
    __syncthreads();
    // global alloc + local scan
    int own = lhist[t];
    if (own > 0) gbase[t] = atomicAdd(&bcur[t], own);
    lbase[t] = own;
    __syncthreads();
    for (int off = 1; off < 512; off <<= 1) {
        int v = (t >= off) ? lbase[t - off] : 0;
        __syncthreads();
        lbase[t] += v;
        __syncthreads();
    }
    int ex = lbase[t] - own;
    __syncthreads();
    lbase[t] = ex;
    __syncthreads();
    // phase 2: scatter into LDS (bucket-ordered), record bucket id
    for (int e = base + t; e < end; e += 512) {
        int r = row[e], c = col[e];
        int gb = c >> BSH2;
        int rk = atomicAdd(&lcur[gb], 1);
        int pos = lbase[gb] + rk;
        buf[pos] = r | ((c & (BNODES - 1)) << 24);
        bof[pos] = (unsigned short)gb;
    }
    __syncthreads();
    // phase 3: flat copy-out (full lane utilization; coalesced within bucket runs)
    int m = end - base;
    for (int k = t; k < m; k += 512) {
        int gb = bof[k];
        packed[gbase[gb] + (k - lbase[gb])] = buf[k];
    }
}

// per-bucket CSR finalize: LDS count -> cnt + ptr; LDS-scatter -> coalesced rows_sorted
__global__ __launch_bounds__(512) void k_csr(
    int* __restrict__ cnt, const int* __restrict__ bstart,
    const int* __restrict__ packed, int* __restrict__ ptr,
    int* __restrict__ rows_sorted, int n, int nb) {
    __shared__ int sh[BNODES];
    __shared__ int lcur[BNODES];
    __shared__ int lrows[CAP];
    int b = blockIdx.x, t = threadIdx.x;
    int c0 = b << BSH2;
    int nloc = min(BNODES, n - c0);
    int s = bstart[b], e = bstart[b + 1];
    int m = e - s;
    if (t < BNODES) sh[t] = 0;
    __syncthreads();
    for (int k = t; k < m; k += 512)
        atomicAdd(&sh[((unsigned)packed[s + k]) >> 24], 1);
    __syncthreads();
    int own = (t < BNODES) ? sh[t] : 0;
    if (t < nloc) cnt[c0 + t] = own;
    for (int off = 1; off < BNODES; off <<= 1) {
        int v = (t >= off && t < BNODES) ? sh[t - off] : 0;
        __syncthreads();
        if (t < BNODES) sh[t] += v;
        __syncthreads();
    }
    if (t < nloc) {
        int ex = sh[t] - own;
        ptr[c0 + t] = s + ex;
        lcur[t] = ex;
    }
    if (b == nb - 1 && t == 0) ptr[n] = e;
    __syncthreads();
    if (m <= CAP) {
        for (int k = t; k < m; k += 512) {
            int p = packed[s + k];
            int pos = atomicAdd(&lcur[((unsigned)p) >> 24], 1);
            lrows[pos] = p & 0xFFFFFF;
        }
        __syncthreads();
        for (int k = t; k < m; k += 512) rows_sorted[s + k] = lrows[k];
    } else {
        for (int k = t; k < m; k += 512) {
            int p = packed[s + k];
            int pos = atomicAdd(&lcur[((unsigned)p) >> 24], 1);
            rows_sorted[s + pos] = p & 0xFFFFFF;
        }
    }
}

// quarter-K GEMM: partial[quarter][node][HID]
#define STEP(av, kk) \
    _Pragma("unroll") for (int j = 0; j < HID; ++j) acc[j] = fmaf(av, w[(kk) * HID + j], acc[j]);

__global__ __launch_bounds__(256) void k_gemm1(
    const float* __restrict__ x, const float* __restrict__ W1,
    float* __restrict__ yp4, int n) {
    int node = blockIdx.x * blockDim.x + threadIdx.x;
    if (node >= n) return;
    int part = blockIdx.y;
    const float* xr = x + (size_t)node * F_IN + part * KH;
    const float* Wb = W1 + (size_t)part * KH * HID;
    float acc[HID];
#pragma unroll
    for (int j = 0; j < HID; ++j) acc[j] = 0.f;
    for (int k = 0; k < KH; k += 16) {
        const float4* xv = reinterpret_cast<const float4*>(xr + k);
        float4 a0 = xv[0], a1 = xv[1], a2 = xv[2], a3 = xv[3];
        const float* w = Wb + (size_t)k * HID;
        STEP(a0.x, 0)  STEP(a0.y, 1)  STEP(a0.z, 2)  STEP(a0.w, 3)
        STEP(a1.x, 4)  STEP(a1.y, 5)  STEP(a1.z, 6)  STEP(a1.w, 7)
        STEP(a2.x, 8)  STEP(a2.y, 9)  STEP(a2.z, 10) STEP(a2.w, 11)
        STEP(a3.x, 12) STEP(a3.y, 13) STEP(a3.z, 14) STEP(a3.w, 15)
    }
    float* o = yp4 + ((size_t)part * n + node) * HID;
    float4* o4 = reinterpret_cast<float4*>(o);
#pragma unroll
    for (int q = 0; q < 4; ++q)
        o4[q] = make_float4(acc[4 * q], acc[4 * q + 1], acc[4 * q + 2], acc[4 * q + 3]);
}

// yp = dinv * (p0 + p1 + p2 + p3)
__global__ void k_comb(const float* __restrict__ yp4, const int* __restrict__ cnt,
                       float* __restrict__ yp, int n) {
    int i = blockIdx.x * blockDim.x + threadIdx.x;   // one float4 per thread
    if (i >= n * 4) return;
    int node = i >> 2;
    float di = rsqrtf((float)(cnt[node] + 1));
    size_t S = (size_t)n * 4;   // float4 stride per partial
    const float4* p = reinterpret_cast<const float4*>(yp4);
    float4 a = p[i], b = p[i + S], c = p[i + 2 * S], d = p[i + 3 * S];
    reinterpret_cast<float4*>(yp)[i] =
        make_float4(di * (a.x + b.x + c.x + d.x), di * (a.y + b.y + c.y + d.y),
                    di * (a.z + b.z + c.z + d.z), di * (a.w + b.w + c.w + d.w));
}

// Gather-reduce over CSR segment. 4 lanes per node; 4-edge unroll for MLP.
template <bool RELU>
__global__ void k_agg(const int* __restrict__ ptr, const int* __restrict__ rows_sorted,
                      const float* __restrict__ src, const int* __restrict__ cnt,
                      const float* __restrict__ b1, float* __restrict__ dst, int n) {
    int t = blockIdx.x * blockDim.x + threadIdx.x;
    int g = t >> 2;
    if (g >= n) return;
    int q = (t & 3) << 2;
    float4 acc = *reinterpret_cast<const float4*>(src + (size_t)g * HID + q);
    int s = ptr[g], e2 = ptr[g + 1];
    int k = s;
    for (; k + 3 < e2; k += 4) {
        int r0 = rows_sorted[k],     r1 = rows_sorted[k + 1];
        int r2 = rows_sorted[k + 2], r3 = rows_sorted[k + 3];
        float4 v0 = *reinterpret_cast<const float4*>(src + (size_t)r0 * HID + q);
        float4 v1 = *reinterpret_cast<const float4*>(src + (size_t)r1 * HID + q);
        float4 v2 = *reinterpret_cast<const float4*>(src + (size_t)r2 * HID + q);
        float4 v3 = *reinterpret_cast<const float4*>(src + (size_t)r3 * HID + q);
        acc.x += (v0.x + v1.x) + (v2.x + v3.x);
        acc.y += (v0.y + v1.y) + (v2.y + v3.y);
        acc.z += (v0.z + v1.z) + (v2.z + v3.z);
        acc.w += (v0.w + v1.w) + (v2.w + v3.w);
    }
    for (; k < e2; ++k) {
        int r0 = rows_sorted[k];
        float4 v0 = *reinterpret_cast<const float4*>(src + (size_t)r0 * HID + q);
        acc.x += v0.x; acc.y += v0.y; acc.z += v0.z; acc.w += v0.w;
    }
    float d = rsqrtf((float)(cnt[g] + 1));
    float4 o;
    if (RELU) {
        float4 bb = *reinterpret_cast<const float4*>(b1 + q);
        o.x = d * fmaxf(fmaf(d, acc.x, bb.x), 0.f);
        o.y = d * fmaxf(fmaf(d, acc.y, bb.y), 0.f);
        o.z = d * fmaxf(fmaf(d, acc.z, bb.z), 0.f);
        o.w = d * fmaxf(fmaf(d, acc.w, bb.w), 0.f);
    } else {
        o.x = d * acc.x; o.y = d * acc.y; o.z = d * acc.z; o.w = d * acc.w;
    }
    *reinterpret_cast<float4*>(dst + (size_t)g * HID + q) = o;
}

// out = log_softmax(agg2 @ W2 + b2)
__global__ void k_final(const float* __restrict__ agg2, const float* __restrict__ W2,
                        const float* __restrict__ b2, float* __restrict__ out, int n) {
    int node = blockIdx.x * blockDim.x + threadIdx.x;
    if (node >= n) return;
    const float4* ar = reinterpret_cast<const float4*>(agg2 + (size_t)node * HID);
    float a[HID];
#pragma unroll
    for (int q = 0; q < 4; ++q) {
        float4 t = ar[q];
        a[4 * q] = t.x; a[4 * q + 1] = t.y; a[4 * q + 2] = t.z; a[4 * q + 3] = t.w;
    }
    float z[NCLS];
#pragma unroll
    for (int j = 0; j < NCLS; ++j) z[j] = b2[j];
#pragma unroll
    for (int i = 0; i < HID; ++i) {
        const float* w = W2 + (size_t)i * NCLS;
        float ai = a[i];
#pragma unroll
        for (int j = 0; j < NCLS; ++j) z[j] = fmaf(ai, w[j], z[j]);
    }
    float m = z[0];
#pragma unroll
    for (int j = 1; j < NCLS; ++j) m = fmaxf(m, z[j]);
    float s = 0.f;
#pragma unroll
    for (int j = 0; j < NCLS; ++j) s += __expf(z[j] - m);
    float ls = m + __logf(s);
    float* o = out + (size_t)node * NCLS;
#pragma unroll
    for (int q = 0; q < NCLS / 4; ++q)
        *reinterpret_cast<float4*>(o + 4 * q) =
            make_float4(z[4 * q] - ls, z[4 * q + 1] - ls, z[4 * q + 2] - ls, z[4 * q + 3] - ls);
}

extern "C" void kernel_launch(void* const* d_in, const int* in_sizes, int n_in,
                              void* d_out, int out_size, void* d_ws, size_t ws_size,
                              hipStream_t stream) {
    const float* x  = (const float*)d_in[0];
    const int*   ei = (const int*)d_in[1];
    const float* W1 = (const float*)d_in[2];
    const float* b1 = (const float*)d_in[3];
    const float* W2 = (const float*)d_in[4];
    const float* b2 = (const float*)d_in[5];
    float* out = (float*)d_out;

    const int N = in_sizes[0] / F_IN;   // 100000
    const int E = in_sizes[1] / 2;      // 3200000
    const int* row = ei;
    const int* col = ei + E;
    const int NBUCK = (N + BNODES - 1) >> BSH2;   // 391

    char* w = (char*)d_ws;
    int*   cnt    = (int*)w;   w += (size_t)N * 4;
    int*   bcnt   = (int*)w;   w += (size_t)NBMAX * 4;
    int*   bstart = (int*)w;   w += (size_t)(NBMAX + 1) * 4;
    int*   bcur   = (int*)w;   w += (size_t)NBMAX * 4;
    int*   ptr    = (int*)w;   w += (size_t)(N + 1) * 4;
    int*   rows_sorted = (int*)w; w += (size_t)E * 4;
    int*   packed = (int*)w;   w += (size_t)E * 4;
    float* yp4    = (float*)w; w += (size_t)KSPL * N * HID * 4;
    float* yp     = (float*)w; w += (size_t)N * HID * 4;
    float* hp     = (float*)w; w += (size_t)N * HID * 4;
    float* agg2   = yp;        // alias (yp dead after layer-1 agg)

    const int B = 256;
    const int NEB = (E + EPB - 1) / EPB;   // 391 edge blocks
    k_zero_i<<<(NBMAX + B - 1) / B, B, 0, stream>>>(bcnt, NBMAX);
    k_bhist <<<NEB, B, 0, stream>>>(col, bcnt, E);
    k_bscan <<<1, 512, 0, stream>>>(bcnt, bstart, bcur, NBUCK);
    k_bucket<<<NEB, 512, 0, stream>>>(row, col, bcur, packed, E);
    k_csr   <<<NBUCK, 512, 0, stream>>>(cnt, bstart, packed, ptr, rows_sorted, N, NBUCK);
    k_gemm1 <<<dim3((N + B - 1) / B, KSPL), B, 0, stream>>>(x, W1, yp4, N);
    k_comb  <<<((N * 4) + B - 1) / B, B, 0, stream>>>(yp4, cnt, yp, N);
    k_agg<true> <<<((N * 4) + B - 1) / B, B, 0, stream>>>(ptr, rows_sorted, yp, cnt, b1, hp, N);
    k_agg<false><<<((N * 4) + B - 1) / B, B, 0, stream>>>(ptr, rows_sorted, hp, cnt, nullptr, agg2, N);
    k_final <<<(N + B - 1) / B, B, 0, stream>>>(agg2, W2, b2, out, N);
}